// Round 11
// baseline (831.135 us; speedup 1.0000x reference)
//
#include <hip/hip_runtime.h>
#include <hip/hip_cooperative_groups.h>

namespace cg = cooperative_groups;

typedef unsigned short ushort_t;
typedef unsigned int uint_t;

typedef __bf16 bf16x8 __attribute__((ext_vector_type(8)));
typedef float f32x4 __attribute__((ext_vector_type(4)));

#define N_NODES 50000
#define N_EDGES 800000
#define DIM 128
#define NUM_GRAPHS 512
#define LDA 136  // padded LDS row stride in bf16 elems (128+8)

// ELL adjacency: fixed 64 slots per node, USHORT entries (src < 2^16).
#define ELL_CAP 64

// Ledger (R3-R10):
//  - R5/R10 edge build = fastest measured (prep 391 blocks rank+reserve,
//    scatter per-bucket LDS counters). ushort ELL = win. Sorting = CLOSED.
//  - R2: fusing gather into a small GEMM grid kills occupancy. Mega-kernel
//    here keeps agg grid-strided at 24 waves/CU.
//  - R8: in_sizes are ELEMENT COUNTS -> dtype detected from bits, per-block.
//  - R10 = 227us, all kernels < 44us -> remaining lever is the 7 dispatch
//    gaps; this round: cooperative mega-kernel (2 dispatches total) with
//    host fallback to the R10 sequence if cooperative launch fails.
#define NBUCK 256
#define BUCK_SZ 196          // ceil(50000/256)
#define FIFO_CAP 4096        // avg 3125/bucket, sigma ~56
#define A_CHUNK 2048
#define A_BLOCKS ((N_EDGES + A_CHUNK - 1) / A_CHUNK)             // 391

#define PREP_X_BLOCKS 6250
#define PREP_W_BLOCKS 256
#define PREP_B_BLOCKS 196
#define PREP_TOTAL (A_BLOCKS + PREP_X_BLOCKS + PREP_W_BLOCKS + PREP_B_BLOCKS + 1)

#define AGG_VBLOCKS ((N_NODES + 15) / 16)   // 3125
#define MLP_VBLOCKS ((N_NODES + 63) / 64)   // 782
#define FC_VBLOCKS (NUM_GRAPHS / 4)         // 128 (4 waves/block, 1 graph/wave)

#define SMEM_BYTES (64 * LDA * 2)           // 17408: max over phases

__device__ __forceinline__ float bf2f(ushort_t u) {
    return __uint_as_float(((uint_t)u) << 16);
}
__device__ __forceinline__ ushort_t f2bf(float f) {
    uint_t u = __float_as_uint(f);
    u = (u + 0x7FFF + ((u >> 16) & 1)) >> 16;  // RNE
    return (ushort_t)u;
}
__device__ __forceinline__ bf16x8 as_bf16x8(uint4 v) {
    return __builtin_bit_cast(bf16x8, v);
}

// ---------------- dtype detection from input bits (R8 lesson) ----------------
__device__ __forceinline__ void detect_flags(const void* xraw, const void* eiraw,
                                             int* f32f, int* i64f) {
    const ushort_t* u = (const ushort_t*)xraw;
    int extreme = 0;
    for (int k = 0; k < 128; ++k) {
        int e = (u[k] >> 7) & 0xFF;
        if (e >= 0xC0) extreme++;  // |x| >= 2^65: impossible for bf16 N(0,1)
    }
    *f32f = (extreme > 8) ? 1 : 0;
    const int* p = (const int*)eiraw;
    int nonzero = 0;
    for (int k = 1; k < 64; k += 2) nonzero += (p[k] != 0);
    *i64f = (nonzero == 0) ? 1 : 0;  // all high-halves zero => int64
}

// ---------------- phase: canonicalization + edge partition (pass A) ----------
__device__ __forceinline__ void dev_prep(
    int b, int tid, char* smemc,
    const void* xraw, const void* braw, const void* eiraw,
    const void* W0, const void* W1, const void* W2, const void* W3,
    const void* pb1a, const void* pb1b, const void* pb2a, const void* pb2b,
    const void* pWfc, const void* pbfc, int f32f, int i64f, int xblocks,
    ushort_t* xout, ushort_t* wpout, int* batch32, float* params,
    int* gcnt, uint_t* fifo) {
    int* lcnt = (int*)smemc;
    int* lbase = lcnt + NBUCK;
    if (b < A_BLOCKS) {
        lcnt[tid] = 0;
        __syncthreads();
        const int* p = (const int*)eiraw;
        int base_e = b * A_CHUNK;
        int gk[8], rk[8];
        uint_t pk[8];
#pragma unroll
        for (int k = 0; k < 8; ++k) {
            int e = base_e + k * 256 + tid;
            int valid = e < N_EDGES;
            int s = 0, d = 0;
            if (valid) {
                if (i64f) { s = p[2 * e]; d = p[2 * (N_EDGES + e)]; }
                else      { s = p[e];     d = p[N_EDGES + e]; }
            }
            int g = d / BUCK_SZ;
            gk[k] = valid ? g : -1;
            pk[k] = (uint_t)s | ((uint_t)(d - g * BUCK_SZ) << 16);
            rk[k] = valid ? atomicAdd(&lcnt[g], 1) : 0;
        }
        __syncthreads();
        lbase[tid] = atomicAdd(&gcnt[tid], lcnt[tid]);  // block reservation
        __syncthreads();
#pragma unroll
        for (int k = 0; k < 8; ++k) {
            if (gk[k] >= 0) {
                int pos = lbase[gk[k]] + rk[k];
                if (pos < FIFO_CAP)
                    fifo[(size_t)gk[k] * FIFO_CAP + pos] = pk[k];
            }
        }
    } else if (b < A_BLOCKS + xblocks) {
        if (f32f) {
            int i = (b - A_BLOCKS) * 256 + tid;
            if (i < N_NODES * DIM / 4) {
                float4 v = ((const float4*)xraw)[i];
                ushort4 o;
                o.x = f2bf(v.x); o.y = f2bf(v.y); o.z = f2bf(v.z); o.w = f2bf(v.w);
                ((ushort4*)xout)[i] = o;
            }
        }
    } else if (b < A_BLOCKS + xblocks + PREP_W_BLOCKS) {
        int gidx = (b - A_BLOCKS - xblocks) * 256 + tid;  // 0..65535
        int which = gidx >> 14;
        const void* W = (which == 0) ? W0 : (which == 1) ? W1 : (which == 2) ? W2 : W3;
        int idx = gidx & 16383;
        int j = idx & 7;
        int L = (idx >> 3) & 63;
        int t = (idx >> 9) & 7;
        int s = idx >> 12;
        int k = s * 32 + (L >> 4) * 8 + j;
        int n = t * 16 + (L & 15);
        int off = k * DIM + n;
        wpout[gidx] = f32f ? f2bf(((const float*)W)[off]) : ((const ushort_t*)W)[off];
    } else if (b < A_BLOCKS + xblocks + PREP_W_BLOCKS + PREP_B_BLOCKS) {
        int i = (b - A_BLOCKS - xblocks - PREP_W_BLOCKS) * 256 + tid;
        if (i < N_NODES) {
            const int* p = (const int*)braw;
            batch32[i] = i64f ? p[2 * i] : p[i];
        }
    } else {
        for (int i = tid; i < 770; i += 256) {
            const void* srcp;
            int j;
            if (i < 128)      { srcp = pb1a; j = i; }
            else if (i < 256) { srcp = pb1b; j = i - 128; }
            else if (i < 384) { srcp = pb2a; j = i - 256; }
            else if (i < 512) { srcp = pb2b; j = i - 384; }
            else if (i < 768) { srcp = pWfc; j = i - 512; }
            else              { srcp = pbfc; j = i - 768; }
            params[i] = f32f ? ((const float*)srcp)[j] : bf2f(((const ushort_t*)srcp)[j]);
        }
    }
}

// ---------------- phase: per-bucket ELL scatter (LDS slot counters) ----------
__device__ __forceinline__ void dev_scatter(int b, int tid, char* smemc,
                                            const uint_t* fifo, const int* gcnt,
                                            int* cnt, ushort_t* ell) {
    int* lcnt = (int*)smemc;
    if (tid < BUCK_SZ) lcnt[tid] = 0;
    __syncthreads();
    int n = gcnt[b];
    if (n > FIFO_CAP) n = FIFO_CAP;
    const uint_t* f = fifo + (size_t)b * FIFO_CAP;
    int node0 = b * BUCK_SZ;
    for (int i = tid; i < n; i += 256) {
        uint_t e = f[i];
        int dl = (int)(e >> 16);
        int slot = atomicAdd(&lcnt[dl], 1);
        if (slot < ELL_CAP)
            ell[(size_t)(node0 + dl) * ELL_CAP + slot] = (ushort_t)(e & 0xFFFFu);
    }
    __syncthreads();
    if (tid < BUCK_SZ) {
        int node = node0 + tid;
        if (node < N_NODES) {
            int deg = lcnt[tid];
            cnt[node] = (deg > ELL_CAP) ? ELL_CAP : deg;
        }
    }
}

// ---------------- phase: aggregation (quarter-wave gather, ushort ELL) -------
__device__ __forceinline__ void dev_agg(int b, int tid, const ushort_t* feat,
                                        const int* deg, const ushort_t* ell,
                                        ushort_t* hout) {
    int n = b * 16 + (tid >> 4);
    int lane = tid & 15;
    if (n >= N_NODES) return;
    const uint4* fp = reinterpret_cast<const uint4*>(feat);  // row = 16 x uint4
    uint4 v = fp[(size_t)n * 16 + lane];
    float a0 = bf2f((ushort_t)(v.x & 0xffff));
    float a1 = bf2f((ushort_t)(v.x >> 16));
    float a2 = bf2f((ushort_t)(v.y & 0xffff));
    float a3 = bf2f((ushort_t)(v.y >> 16));
    float a4 = bf2f((ushort_t)(v.z & 0xffff));
    float a5 = bf2f((ushort_t)(v.z >> 16));
    float a6 = bf2f((ushort_t)(v.w & 0xffff));
    float a7 = bf2f((ushort_t)(v.w >> 16));
    int e1 = deg[n];  // already capped at ELL_CAP by scatter
    const uint4* rp4 = reinterpret_cast<const uint4*>(ell + (size_t)n * ELL_CAP);
    const ushort_t* row = ell + (size_t)n * ELL_CAP;
    int j = 0;
#define ACC8(V) \
    a0 += bf2f((ushort_t)((V).x & 0xffff)); a1 += bf2f((ushort_t)((V).x >> 16)); \
    a2 += bf2f((ushort_t)((V).y & 0xffff)); a3 += bf2f((ushort_t)((V).y >> 16)); \
    a4 += bf2f((ushort_t)((V).z & 0xffff)); a5 += bf2f((ushort_t)((V).z >> 16)); \
    a6 += bf2f((ushort_t)((V).w & 0xffff)); a7 += bf2f((ushort_t)((V).w >> 16));
    for (; j + 8 <= e1; j += 8) {
        uint4 ra = rp4[j >> 3];  // 8 packed ushort indices
        int s0 = (int)(ra.x & 0xffff), s1 = (int)(ra.x >> 16);
        int s2 = (int)(ra.y & 0xffff), s3 = (int)(ra.y >> 16);
        int s4 = (int)(ra.z & 0xffff), s5 = (int)(ra.z >> 16);
        int s6 = (int)(ra.w & 0xffff), s7 = (int)(ra.w >> 16);
        uint4 g0 = fp[(size_t)s0 * 16 + lane];
        uint4 g1 = fp[(size_t)s1 * 16 + lane];
        uint4 g2 = fp[(size_t)s2 * 16 + lane];
        uint4 g3 = fp[(size_t)s3 * 16 + lane];
        uint4 g4 = fp[(size_t)s4 * 16 + lane];
        uint4 g5 = fp[(size_t)s5 * 16 + lane];
        uint4 g6 = fp[(size_t)s6 * 16 + lane];
        uint4 g7 = fp[(size_t)s7 * 16 + lane];
        ACC8(g0) ACC8(g1) ACC8(g2) ACC8(g3)
        ACC8(g4) ACC8(g5) ACC8(g6) ACC8(g7)
    }
    if (j + 4 <= e1) {
        uint2 ra = *reinterpret_cast<const uint2*>(row + j);
        int s0 = (int)(ra.x & 0xffff), s1 = (int)(ra.x >> 16);
        int s2 = (int)(ra.y & 0xffff), s3 = (int)(ra.y >> 16);
        uint4 g0 = fp[(size_t)s0 * 16 + lane];
        uint4 g1 = fp[(size_t)s1 * 16 + lane];
        uint4 g2 = fp[(size_t)s2 * 16 + lane];
        uint4 g3 = fp[(size_t)s3 * 16 + lane];
        ACC8(g0) ACC8(g1) ACC8(g2) ACC8(g3)
        j += 4;
    }
    for (; j < e1; ++j) {
        int s = (int)row[j];
        uint4 g0 = fp[(size_t)s * 16 + lane];
        ACC8(g0)
    }
#undef ACC8
    uint4 o;
    o.x = (uint_t)f2bf(a0) | ((uint_t)f2bf(a1) << 16);
    o.y = (uint_t)f2bf(a2) | ((uint_t)f2bf(a3) << 16);
    o.z = (uint_t)f2bf(a4) | ((uint_t)f2bf(a5) << 16);
    o.w = (uint_t)f2bf(a6) | ((uint_t)f2bf(a7) << 16);
    reinterpret_cast<uint4*>(hout)[(size_t)n * 16 + lane] = o;
}

// ---------------- phase: fused MLP (B2 loaded late: non-overlapping B lives) --
__device__ __forceinline__ void dev_mlp(int b, int tid, char* smemc,
                                        const ushort_t* hin, const ushort_t* wpA,
                                        const float* ba, const ushort_t* wpB,
                                        const float* bb, ushort_t* hout) {
    ushort_t* As = (ushort_t*)smemc;
    int wave = tid >> 6, lane = tid & 63, quad = lane >> 4, cl = lane & 15;
    int row0 = b * 64;
    bf16x8 B[2][4];
#pragma unroll
    for (int ti = 0; ti < 2; ++ti) {
        int t = 2 * wave + ti;
#pragma unroll
        for (int s = 0; s < 4; ++s)
            B[ti][s] = as_bf16x8(reinterpret_cast<const uint4*>(wpA)[(s * 8 + t) * 64 + lane]);
    }
    for (int i = tid; i < 64 * 16; i += 256) {
        int r = i >> 4, c8 = i & 15;
        uint4 v = make_uint4(0u, 0u, 0u, 0u);
        int gr = row0 + r;
        if (gr < N_NODES)
            v = reinterpret_cast<const uint4*>(hin + (size_t)gr * DIM)[c8];
        *reinterpret_cast<uint4*>(&As[r * LDA + c8 * 8]) = v;
    }
    __syncthreads();
    f32x4 acc[4][2];
#pragma unroll
    for (int m = 0; m < 4; ++m)
#pragma unroll
        for (int ti = 0; ti < 2; ++ti)
#pragma unroll
            for (int r = 0; r < 4; ++r) acc[m][ti][r] = 0.f;
#pragma unroll
    for (int s = 0; s < 4; ++s)
#pragma unroll
        for (int m = 0; m < 4; ++m) {
            bf16x8 a = *reinterpret_cast<const bf16x8*>(&As[(m * 16 + cl) * LDA + s * 32 + quad * 8]);
#pragma unroll
            for (int ti = 0; ti < 2; ++ti)
                acc[m][ti] = __builtin_amdgcn_mfma_f32_16x16x32_bf16(a, B[ti][s], acc[m][ti], 0, 0, 0);
        }
    __syncthreads();
#pragma unroll
    for (int ti = 0; ti < 2; ++ti) {
        int col = 32 * wave + ti * 16 + cl;
        float bv = ba[col];
#pragma unroll
        for (int m = 0; m < 4; ++m)
#pragma unroll
            for (int r = 0; r < 4; ++r) {
                float v = acc[m][ti][r] + bv;
                As[(m * 16 + quad * 4 + r) * LDA + col] = f2bf(fmaxf(v, 0.f));
            }
    }
    __syncthreads();
#pragma unroll
    for (int ti = 0; ti < 2; ++ti) {  // B2 loaded late (register-live-range)
        int t = 2 * wave + ti;
#pragma unroll
        for (int s = 0; s < 4; ++s)
            B[ti][s] = as_bf16x8(reinterpret_cast<const uint4*>(wpB)[(s * 8 + t) * 64 + lane]);
    }
#pragma unroll
    for (int m = 0; m < 4; ++m)
#pragma unroll
        for (int ti = 0; ti < 2; ++ti)
#pragma unroll
            for (int r = 0; r < 4; ++r) acc[m][ti][r] = 0.f;
#pragma unroll
    for (int s = 0; s < 4; ++s)
#pragma unroll
        for (int m = 0; m < 4; ++m) {
            bf16x8 a = *reinterpret_cast<const bf16x8*>(&As[(m * 16 + cl) * LDA + s * 32 + quad * 8]);
#pragma unroll
            for (int ti = 0; ti < 2; ++ti)
                acc[m][ti] = __builtin_amdgcn_mfma_f32_16x16x32_bf16(a, B[ti][s], acc[m][ti], 0, 0, 0);
        }
#pragma unroll
    for (int ti = 0; ti < 2; ++ti) {
        int col = 32 * wave + ti * 16 + cl;
        float bv = bb[col];
#pragma unroll
        for (int m = 0; m < 4; ++m)
#pragma unroll
            for (int r = 0; r < 4; ++r) {
                int gr = row0 + m * 16 + quad * 4 + r;
                if (gr < N_NODES) {
                    float v = acc[m][ti][r] + bv;
                    hout[(size_t)gr * DIM + col] = f2bf(fmaxf(v, 0.f));
                }
            }
    }
    __syncthreads();  // As safe for next grid-stride iteration
}

// ---------------- phase: fused MLP layer 2 + per-graph pooling ----------------
__device__ __forceinline__ void dev_mlp_pool(int b, int tid, char* smemc,
                                             const ushort_t* hin, const ushort_t* wpA,
                                             const float* ba, const ushort_t* wpB,
                                             const float* bb, const int* batch32,
                                             float* gsum) {
    ushort_t* As = (ushort_t*)smemc;
    int wave = tid >> 6, lane = tid & 63, quad = lane >> 4, cl = lane & 15;
    int row0 = b * 64;
    bf16x8 B[2][4];
#pragma unroll
    for (int ti = 0; ti < 2; ++ti) {
        int t = 2 * wave + ti;
#pragma unroll
        for (int s = 0; s < 4; ++s)
            B[ti][s] = as_bf16x8(reinterpret_cast<const uint4*>(wpA)[(s * 8 + t) * 64 + lane]);
    }
    for (int i = tid; i < 64 * 16; i += 256) {
        int r = i >> 4, c8 = i & 15;
        uint4 v = make_uint4(0u, 0u, 0u, 0u);
        int gr = row0 + r;
        if (gr < N_NODES)
            v = reinterpret_cast<const uint4*>(hin + (size_t)gr * DIM)[c8];
        *reinterpret_cast<uint4*>(&As[r * LDA + c8 * 8]) = v;
    }
    __syncthreads();
    f32x4 acc[4][2];
#pragma unroll
    for (int m = 0; m < 4; ++m)
#pragma unroll
        for (int ti = 0; ti < 2; ++ti)
#pragma unroll
            for (int r = 0; r < 4; ++r) acc[m][ti][r] = 0.f;
#pragma unroll
    for (int s = 0; s < 4; ++s)
#pragma unroll
        for (int m = 0; m < 4; ++m) {
            bf16x8 a = *reinterpret_cast<const bf16x8*>(&As[(m * 16 + cl) * LDA + s * 32 + quad * 8]);
#pragma unroll
            for (int ti = 0; ti < 2; ++ti)
                acc[m][ti] = __builtin_amdgcn_mfma_f32_16x16x32_bf16(a, B[ti][s], acc[m][ti], 0, 0, 0);
        }
    __syncthreads();
#pragma unroll
    for (int ti = 0; ti < 2; ++ti) {
        int col = 32 * wave + ti * 16 + cl;
        float bv = ba[col];
#pragma unroll
        for (int m = 0; m < 4; ++m)
#pragma unroll
            for (int r = 0; r < 4; ++r) {
                float v = acc[m][ti][r] + bv;
                As[(m * 16 + quad * 4 + r) * LDA + col] = f2bf(fmaxf(v, 0.f));
            }
    }
    __syncthreads();
#pragma unroll
    for (int ti = 0; ti < 2; ++ti) {  // B2 late
        int t = 2 * wave + ti;
#pragma unroll
        for (int s = 0; s < 4; ++s)
            B[ti][s] = as_bf16x8(reinterpret_cast<const uint4*>(wpB)[(s * 8 + t) * 64 + lane]);
    }
#pragma unroll
    for (int m = 0; m < 4; ++m)
#pragma unroll
        for (int ti = 0; ti < 2; ++ti)
#pragma unroll
            for (int r = 0; r < 4; ++r) acc[m][ti][r] = 0.f;
#pragma unroll
    for (int s = 0; s < 4; ++s)
#pragma unroll
        for (int m = 0; m < 4; ++m) {
            bf16x8 a = *reinterpret_cast<const bf16x8*>(&As[(m * 16 + cl) * LDA + s * 32 + quad * 8]);
#pragma unroll
            for (int ti = 0; ti < 2; ++ti)
                acc[m][ti] = __builtin_amdgcn_mfma_f32_16x16x32_bf16(a, B[ti][s], acc[m][ti], 0, 0, 0);
        }
    __syncthreads();  // all As reads of GEMM2 done before epilogue overwrite
#pragma unroll
    for (int ti = 0; ti < 2; ++ti) {
        int col = 32 * wave + ti * 16 + cl;
        float bv = bb[col];
#pragma unroll
        for (int m = 0; m < 4; ++m)
#pragma unroll
            for (int r = 0; r < 4; ++r) {
                float v = acc[m][ti][r] + bv;
                As[(m * 16 + quad * 4 + r) * LDA + col] = f2bf(fmaxf(v, 0.f));
            }
    }
    __syncthreads();
    // pooling: thread t handles col c over 32 rows; flush per graph segment
    int c = tid & 127;
    int rbase = (tid >> 7) * 32;
    float accp = 0.f;
    int curg = -1;
    for (int r = rbase; r < rbase + 32; ++r) {
        int gr = row0 + r;
        if (gr >= N_NODES) break;
        int g = batch32[gr];
        if (g != curg) {
            if (curg >= 0) atomicAdd(&gsum[curg * DIM + c], accp);
            curg = g;
            accp = 0.f;
        }
        accp += bf2f(As[r * LDA + c]);
    }
    if (curg >= 0) atomicAdd(&gsum[curg * DIM + c], accp);
    __syncthreads();  // As safe for next grid-stride iteration
}

// ---------------- phase: final FC (4 waves/block, 1 graph/wave) ----------------
__device__ __forceinline__ void dev_fc(int vb, int tid, const float* gsum,
                                       const int* batch, const float* params,
                                       int outf32, void* out) {
    int wave = tid >> 6, l = tid & 63;
    int g = vb * 4 + wave;
    if (g >= NUM_GRAPHS) return;
    int lo = 0, hi = N_NODES;
    while (lo < hi) { int mid = (lo + hi) >> 1; if (batch[mid] < g) lo = mid + 1; else hi = mid; }
    int start = lo;
    hi = N_NODES;
    while (lo < hi) { int mid = (lo + hi) >> 1; if (batch[mid] < g + 1) lo = mid + 1; else hi = mid; }
    int cnt = lo - start;
    float inv = 1.0f / (float)(cnt > 0 ? cnt : 1);
    float m0 = gsum[g * DIM + l] * inv;
    float m1 = gsum[g * DIM + 64 + l] * inv;
    float p0 = m0 * params[512 + l * 2 + 0] + m1 * params[512 + (64 + l) * 2 + 0];
    float p1 = m0 * params[512 + l * 2 + 1] + m1 * params[512 + (64 + l) * 2 + 1];
#pragma unroll
    for (int off = 32; off > 0; off >>= 1) {
        p0 += __shfl_down(p0, off, 64);
        p1 += __shfl_down(p1, off, 64);
    }
    if (l == 0) {
        float o0 = p0 + params[768];
        float o1 = p1 + params[769];
        if (outf32) {
            ((float*)out)[g * 2 + 0] = o0;
            ((float*)out)[g * 2 + 1] = o1;
        } else {
            ((ushort_t*)out)[g * 2 + 0] = f2bf(o0);
            ((ushort_t*)out)[g * 2 + 1] = f2bf(o1);
        }
    }
}

// ================= cooperative mega-kernel (2-dispatch path) =================
struct MegaArgs {
    const void *x, *ei, *batch;
    const void *W1a, *b1a, *W1b, *b1b, *W2a, *b2a, *W2b, *b2b, *Wfc, *bfc;
    ushort_t *hX, *hA, *ell;
    uint_t *fifo;
    int *cnt, *batch32, *gcnt;
    ushort_t *wp;
    float *params, *gsum;
    void *out;
};

__global__ __launch_bounds__(256, 6) void mega_kernel(MegaArgs a) {
    cg::grid_group grid = cg::this_grid();
    __shared__ __align__(16) char smem[SMEM_BYTES];
    __shared__ int sflags[2];
    int tid = threadIdx.x;
    if (tid == 0) detect_flags(a.x, a.ei, &sflags[0], &sflags[1]);
    __syncthreads();
    int f32f = sflags[0], i64f = sflags[1];
    int nblk = gridDim.x, bid = blockIdx.x;

    // phase 1: prep (edge partition + canonicalization); skip x-conv when bf16
    int xblocks = f32f ? PREP_X_BLOCKS : 0;
    int ptotal = A_BLOCKS + xblocks + PREP_W_BLOCKS + PREP_B_BLOCKS + 1;
    for (int vb = bid; vb < ptotal; vb += nblk)
        dev_prep(vb, tid, smem, a.x, a.batch, a.ei, a.W1a, a.W1b, a.W2a, a.W2b,
                 a.b1a, a.b1b, a.b2a, a.b2b, a.Wfc, a.bfc, f32f, i64f, xblocks,
                 a.hX, a.wp, a.batch32, a.params, a.gcnt, a.fifo);
    grid.sync();
    // phase 2: scatter
    for (int vb = bid; vb < NBUCK; vb += nblk)
        dev_scatter(vb, tid, smem, a.fifo, a.gcnt, a.cnt, a.ell);
    grid.sync();
    // phase 3: agg layer 1
    const ushort_t* feat0 = f32f ? a.hX : (const ushort_t*)a.x;
    for (int vb = bid; vb < AGG_VBLOCKS; vb += nblk)
        dev_agg(vb, tid, feat0, a.cnt, a.ell, a.hA);
    grid.sync();
    // phase 4: mlp layer 1 (in-place on hA)
    for (int vb = bid; vb < MLP_VBLOCKS; vb += nblk)
        dev_mlp(vb, tid, smem, a.hA, a.wp, a.params + 0, a.wp + 16384,
                a.params + 128, a.hA);
    grid.sync();
    // phase 5: agg layer 2
    for (int vb = bid; vb < AGG_VBLOCKS; vb += nblk)
        dev_agg(vb, tid, a.hA, a.cnt, a.ell, a.hX);
    grid.sync();
    // phase 6: mlp layer 2 + pooling
    for (int vb = bid; vb < MLP_VBLOCKS; vb += nblk)
        dev_mlp_pool(vb, tid, smem, a.hX, a.wp + 2 * 16384, a.params + 256,
                     a.wp + 3 * 16384, a.params + 384, a.batch32, a.gsum);
    grid.sync();
    // phase 7: fc
    for (int vb = bid; vb < FC_VBLOCKS; vb += nblk)
        dev_fc(vb, tid, a.gsum, a.batch32, a.params, f32f, a.out);
}

// ================= standalone kernels (fallback path, same bodies) ===========
__global__ void flags_kernel(const void* xraw, const void* eiraw, int* flags) {
    if (threadIdx.x == 0) detect_flags(xraw, eiraw, &flags[0], &flags[1]);
}

__global__ __launch_bounds__(256) void prep_all_kernel(
    const void* xraw, const void* braw, const void* eiraw,
    const void* W0, const void* W1, const void* W2, const void* W3,
    const void* pb1a, const void* pb1b, const void* pb2a, const void* pb2b,
    const void* pWfc, const void* pbfc, const int* __restrict__ flags,
    ushort_t* xout, ushort_t* wpout, int* batch32, float* params,
    int* gcnt, uint_t* fifo) {
    __shared__ __align__(16) char smem[NBUCK * 8];
    dev_prep(blockIdx.x, threadIdx.x, smem, xraw, braw, eiraw, W0, W1, W2, W3,
             pb1a, pb1b, pb2a, pb2b, pWfc, pbfc, flags[0], flags[1],
             PREP_X_BLOCKS, xout, wpout, batch32, params, gcnt, fifo);
}

__global__ __launch_bounds__(256) void scatter_kernel(const uint_t* fifo,
                                                      const int* gcnt, int* cnt,
                                                      ushort_t* ell) {
    __shared__ __align__(16) char smem[BUCK_SZ * 4];
    dev_scatter(blockIdx.x, threadIdx.x, smem, fifo, gcnt, cnt, ell);
}

__global__ __launch_bounds__(256) void agg_kernel(const ushort_t* featA,
                                                  const void* featB,
                                                  const int* flags,
                                                  const int* deg,
                                                  const ushort_t* ell,
                                                  ushort_t* hout) {
    const ushort_t* feat = featA;
    if (flags && !flags[0]) feat = (const ushort_t*)featB;
    dev_agg(blockIdx.x, threadIdx.x, feat, deg, ell, hout);
}

__global__ __launch_bounds__(256) void mlp_kernel(const ushort_t* hin,
                                                  const ushort_t* wpA, const float* ba,
                                                  const ushort_t* wpB, const float* bb,
                                                  ushort_t* hout) {
    __shared__ __align__(16) char smem[SMEM_BYTES];
    dev_mlp(blockIdx.x, threadIdx.x, smem, hin, wpA, ba, wpB, bb, hout);
}

__global__ __launch_bounds__(256) void mlp_pool_kernel(const ushort_t* hin,
                                                       const ushort_t* wpA, const float* ba,
                                                       const ushort_t* wpB, const float* bb,
                                                       const int* batch32, float* gsum) {
    __shared__ __align__(16) char smem[SMEM_BYTES];
    dev_mlp_pool(blockIdx.x, threadIdx.x, smem, hin, wpA, ba, wpB, bb, batch32, gsum);
}

__global__ __launch_bounds__(256) void fc_kernel(const float* gsum, const int* batch,
                                                 const float* params, const int* flags,
                                                 void* out) {
    dev_fc(blockIdx.x, threadIdx.x, gsum, batch, params, flags[0], out);
}

extern "C" void kernel_launch(void* const* d_in, const int* in_sizes, int n_in,
                              void* d_out, int out_size, void* d_ws, size_t ws_size,
                              hipStream_t stream) {
    const void* x = d_in[0];
    const void* ei = d_in[1];
    const void* batch = d_in[2];
    const void* W1a = d_in[3];
    const void* b1a = d_in[4];
    const void* W1b = d_in[5];
    const void* b1b = d_in[6];
    const void* W2a = d_in[7];
    const void* b2a = d_in[8];
    const void* W2b = d_in[9];
    const void* b2b = d_in[10];
    const void* Wfc = d_in[11];
    const void* bfc = d_in[12];

    // Workspace layout (~38 MB; gsum+gcnt adjacent for one memset)
    char* base = (char*)d_ws;
    ushort_t* hX = (ushort_t*)base;   base += (size_t)N_NODES * DIM * 2;       // 12.8 MB
    ushort_t* hA = (ushort_t*)base;   base += (size_t)N_NODES * DIM * 2;       // 12.8 MB
    ushort_t* ell = (ushort_t*)base;  base += (size_t)N_NODES * ELL_CAP * 2;   // 6.4 MB
    uint_t* fifo = (uint_t*)base;     base += (size_t)NBUCK * FIFO_CAP * 4;    // 4 MB
    int* cnt = (int*)base;            base += (size_t)N_NODES * 4;
    int* batch32 = (int*)base;        base += (size_t)N_NODES * 4;
    ushort_t* wp = (ushort_t*)base;   base += 4 * 16384 * 2;
    float* params = (float*)base;     base += 772 * 4;
    float* gsum = (float*)base;       base += (size_t)NUM_GRAPHS * DIM * 4;    // 256 KB
    int* gcnt = (int*)base;           base += NBUCK * 4;                       // adjacent to gsum
    int* flags = (int*)base;          base += 16;

    ushort_t* wpA1 = wp;
    ushort_t* wpB1 = wp + 16384;
    ushort_t* wpA2 = wp + 2 * 16384;
    ushort_t* wpB2 = wp + 3 * 16384;

    // One memset covers gsum (256KB) + gcnt (1KB), adjacent.
    hipMemsetAsync(gsum, 0, (size_t)NUM_GRAPHS * DIM * 4 + NBUCK * 4, stream);

    MegaArgs ma;
    ma.x = x; ma.ei = ei; ma.batch = batch;
    ma.W1a = W1a; ma.b1a = b1a; ma.W1b = W1b; ma.b1b = b1b;
    ma.W2a = W2a; ma.b2a = b2a; ma.W2b = W2b; ma.b2b = b2b;
    ma.Wfc = Wfc; ma.bfc = bfc;
    ma.hX = hX; ma.hA = hA; ma.ell = ell; ma.fifo = fifo;
    ma.cnt = cnt; ma.batch32 = batch32; ma.gcnt = gcnt;
    ma.wp = wp; ma.params = params; ma.gsum = gsum; ma.out = d_out;
    void* kargs[] = { &ma };

    static int s_cus = 0;
    if (s_cus == 0) {
        hipDeviceProp_t p;
        if (hipGetDeviceProperties(&p, 0) == hipSuccess && p.multiProcessorCount > 0)
            s_cus = p.multiProcessorCount;
        else
            s_cus = 256;
    }
    int occ = 0;
    hipError_t oerr = hipOccupancyMaxActiveBlocksPerMultiprocessor(&occ, mega_kernel, 256, 0);
    bool coop_ok = false;
    if (oerr == hipSuccess && occ >= 1) {
        int grid = occ * s_cus;
        if (grid > 1536) grid = 1536;
        hipError_t lerr = hipLaunchCooperativeKernel((const void*)mega_kernel,
                                                     dim3(grid), dim3(256), kargs, 0, stream);
        coop_ok = (lerr == hipSuccess);
        if (!coop_ok) (void)hipGetLastError();  // clear error state for fallback
    }
    if (!coop_ok) {
        // R10 8-dispatch fallback (same device bodies)
        flags_kernel<<<1, 64, 0, stream>>>(x, ei, flags);
        prep_all_kernel<<<PREP_TOTAL, 256, 0, stream>>>(x, batch, ei, W1a, W1b, W2a, W2b,
                                                        b1a, b1b, b2a, b2b, Wfc, bfc, flags,
                                                        hX, wp, batch32, params, gcnt, fifo);
        scatter_kernel<<<NBUCK, 256, 0, stream>>>(fifo, gcnt, cnt, ell);
        agg_kernel<<<AGG_VBLOCKS, 256, 0, stream>>>(hX, x, flags, cnt, ell, hA);
        mlp_kernel<<<MLP_VBLOCKS, 256, 0, stream>>>(hA, wpA1, params + 0, wpB1, params + 128, hA);
        agg_kernel<<<AGG_VBLOCKS, 256, 0, stream>>>(hA, hA, nullptr, cnt, ell, hX);
        mlp_pool_kernel<<<MLP_VBLOCKS, 256, 0, stream>>>(hX, wpA2, params + 256, wpB2, params + 384,
                                                         batch32, gsum);
        fc_kernel<<<FC_VBLOCKS, 256, 0, stream>>>(gsum, batch32, params, flags, d_out);
    }
}

// Round 12
// 226.662 us; speedup vs baseline: 3.6668x; 3.6668x over previous
//
#include <hip/hip_runtime.h>

typedef unsigned short ushort_t;
typedef unsigned int uint_t;

typedef __bf16 bf16x8 __attribute__((ext_vector_type(8)));
typedef float f32x4 __attribute__((ext_vector_type(4)));

#define N_NODES 50000
#define N_EDGES 800000
#define DIM 128
#define NUM_GRAPHS 512
#define LDA 136  // padded LDS row stride in bf16 elems (128+8)

// ELL adjacency: fixed 64 slots per node, USHORT entries (src < 2^16).
// In-degree ~Poisson(16), max ~35; deg capped at 64 when cnt is written.
#define ELL_CAP 64

// Ledger (R3-R11):
//  - R5/R10 edge build = fastest measured: pass A 391 blocks single-read
//    rank+reserve (~20us), scatter per-bucket LDS slot counters (~5us).
//  - ushort ELL (R6) = win, kept. Capped cnt + gsum-zero in scatter = kept.
//  - band/full sorting of rows (R6/R7/R9): agg gain ~4-6us, producer cost
//    >=16us at every geometry tried -> CLOSED.
//  - 1024-bucket two-phase pass A (R9): 0.4 blocks/CU -> prep 50us. Never.
//  - in_sizes is ELEMENT COUNTS (R8): dtype must be device-detected from bits.
//  - cooperative mega-kernel (R11): grid.sync spin across 8 non-coherent XCD
//    L2s costs >>100us/sync at 1536 blocks -> 831us total. CLOSED.
//  R10 = 227.1us best. This is the R10 configuration, reverted verbatim.
#define NBUCK 256
#define BUCK_SZ 196          // ceil(50000/256)
#define FIFO_CAP 4096        // avg 3125/bucket, sigma ~56 -> huge margin
#define A_CHUNK 2048
#define A_BLOCKS ((N_EDGES + A_CHUNK - 1) / A_CHUNK)             // 391

// prep_all block ranges (edge-partition blocks first: critical path)
#define PREP_X_BLOCKS 6250                    // conv_x: only does work when f32 input
#define PREP_W_BLOCKS 256                     // wperm: 65536 / 256
#define PREP_B_BLOCKS 196                     // batch: 50000 / 256
#define PREP_TOTAL (A_BLOCKS + PREP_X_BLOCKS + PREP_W_BLOCKS + PREP_B_BLOCKS + 1)

__device__ __forceinline__ float bf2f(ushort_t u) {
    return __uint_as_float(((uint_t)u) << 16);
}
__device__ __forceinline__ ushort_t f2bf(float f) {
    uint_t u = __float_as_uint(f);
    u = (u + 0x7FFF + ((u >> 16) & 1)) >> 16;  // RNE
    return (ushort_t)u;
}
__device__ __forceinline__ bf16x8 as_bf16x8(uint4 v) {
    return __builtin_bit_cast(bf16x8, v);
}

// ---------------- zero (gcnt) + dtype detection (device-side; R8 lesson) -------
__global__ void zero_detect_kernel(int* gcnt, const void* xraw,
                                   const void* eiraw, int* flags) {
    int i = threadIdx.x;
    if (i < NBUCK) gcnt[i] = 0;
    if (i == 0) {
        const ushort_t* u = (const ushort_t*)xraw;
        int extreme = 0;
        for (int k = 0; k < 128; ++k) {
            int e = (u[k] >> 7) & 0xFF;
            if (e >= 0xC0) extreme++;  // |x| >= 2^65: impossible for bf16 N(0,1)
        }
        flags[0] = (extreme > 8) ? 1 : 0;
        const int* p = (const int*)eiraw;
        int nonzero = 0;
        for (int k = 1; k < 64; k += 2) nonzero += (p[k] != 0);
        flags[1] = (nonzero == 0) ? 1 : 0;  // all high-halves zero => int64
    }
}

// ---------------- merged canonicalization + edge partition (pass A) ----------------
// R5's proven geometry: 391 edge blocks, single read, register-buffered rank
// via LDS counters + one reservation atomic per (block,bucket).
__global__ __launch_bounds__(256) void prep_all_kernel(
    const void* xraw, const void* braw, const void* eiraw,
    const void* W0, const void* W1, const void* W2, const void* W3,
    const void* pb1a, const void* pb1b, const void* pb2a, const void* pb2b,
    const void* pWfc, const void* pbfc, const int* __restrict__ flags,
    ushort_t* __restrict__ xout, ushort_t* __restrict__ wpout,
    int* __restrict__ batch32, float* __restrict__ params,
    int* __restrict__ gcnt, uint_t* __restrict__ fifo) {
    __shared__ int lcnt[NBUCK];
    __shared__ int lbase[NBUCK];
    int b = blockIdx.x;
    int tid = threadIdx.x;
    if (b < A_BLOCKS) {
        lcnt[tid] = 0;
        __syncthreads();
        const int* p = (const int*)eiraw;
        int i64 = flags[1];
        int base_e = b * A_CHUNK;
        int gk[8], rk[8];
        uint_t pk[8];
#pragma unroll
        for (int k = 0; k < 8; ++k) {
            int e = base_e + k * 256 + tid;
            int valid = e < N_EDGES;
            int s = 0, d = 0;
            if (valid) {
                if (i64) { s = p[2 * e]; d = p[2 * (N_EDGES + e)]; }
                else     { s = p[e];     d = p[N_EDGES + e]; }
            }
            int g = d / BUCK_SZ;                       // 0..255 (magic-mul)
            gk[k] = valid ? g : -1;
            pk[k] = (uint_t)s | ((uint_t)(d - g * BUCK_SZ) << 16);
            rk[k] = valid ? atomicAdd(&lcnt[g], 1) : 0;
        }
        __syncthreads();
        lbase[tid] = atomicAdd(&gcnt[tid], lcnt[tid]);  // block reservation
        __syncthreads();
#pragma unroll
        for (int k = 0; k < 8; ++k) {
            if (gk[k] >= 0) {
                int pos = lbase[gk[k]] + rk[k];
                if (pos < FIFO_CAP)
                    fifo[(size_t)gk[k] * FIFO_CAP + pos] = pk[k];
            }
        }
    } else if (b < A_BLOCKS + PREP_X_BLOCKS) {
        if (flags[0]) {  // only f32 input needs conversion; bf16 is read in place
            int i = (b - A_BLOCKS) * 256 + tid;
            if (i < N_NODES * DIM / 4) {
                float4 v = ((const float4*)xraw)[i];
                ushort4 o;
                o.x = f2bf(v.x); o.y = f2bf(v.y); o.z = f2bf(v.z); o.w = f2bf(v.w);
                ((ushort4*)xout)[i] = o;
            }
        }
    } else if (b < A_BLOCKS + PREP_X_BLOCKS + PREP_W_BLOCKS) {
        int gidx = (b - A_BLOCKS - PREP_X_BLOCKS) * 256 + tid;  // 0..65535
        int which = gidx >> 14;
        const void* W = (which == 0) ? W0 : (which == 1) ? W1 : (which == 2) ? W2 : W3;
        int idx = gidx & 16383;
        int j = idx & 7;
        int L = (idx >> 3) & 63;
        int t = (idx >> 9) & 7;
        int s = idx >> 12;
        int k = s * 32 + (L >> 4) * 8 + j;
        int n = t * 16 + (L & 15);
        int off = k * DIM + n;
        wpout[gidx] = flags[0] ? f2bf(((const float*)W)[off]) : ((const ushort_t*)W)[off];
    } else if (b < A_BLOCKS + PREP_X_BLOCKS + PREP_W_BLOCKS + PREP_B_BLOCKS) {
        int i = (b - A_BLOCKS - PREP_X_BLOCKS - PREP_W_BLOCKS) * 256 + tid;
        if (i < N_NODES) {
            const int* p = (const int*)braw;
            batch32[i] = flags[1] ? p[2 * i] : p[i];
        }
    } else {
        for (int i = tid; i < 770; i += 256) {
            const void* srcp;
            int j;
            if (i < 128)      { srcp = pb1a; j = i; }
            else if (i < 256) { srcp = pb1b; j = i - 128; }
            else if (i < 384) { srcp = pb2a; j = i - 256; }
            else if (i < 512) { srcp = pb2b; j = i - 384; }
            else if (i < 768) { srcp = pWfc; j = i - 512; }
            else              { srcp = pbfc; j = i - 768; }
            params[i] = flags[0] ? ((const float*)srcp)[j] : bf2f(((const ushort_t*)srcp)[j]);
        }
    }
}

// ---------------- pass B: per-bucket ELL scatter with LDS slot counters --------
// Block b exclusively owns nodes [b*196,(b+1)*196): slot RMW in LDS, zero
// global atomics. No sorting (closed: cost >= gain at every geometry).
__global__ __launch_bounds__(256) void scatter_kernel(const uint_t* __restrict__ fifo,
                                                      const int* __restrict__ gcnt,
                                                      int* __restrict__ cnt,
                                                      ushort_t* __restrict__ ell,
                                                      float* __restrict__ gsum) {
    __shared__ int lcnt[BUCK_SZ];
    int b = blockIdx.x;
    int tid = threadIdx.x;
    gsum[b * 256 + tid] = 0.f;  // 256 blocks x 256 threads = 512*128 exactly
    if (tid < BUCK_SZ) lcnt[tid] = 0;
    __syncthreads();
    int n = gcnt[b];
    if (n > FIFO_CAP) n = FIFO_CAP;
    const uint_t* f = fifo + (size_t)b * FIFO_CAP;
    int node0 = b * BUCK_SZ;
    for (int i = tid; i < n; i += 256) {
        uint_t e = f[i];
        int dl = (int)(e >> 16);
        int slot = atomicAdd(&lcnt[dl], 1);
        if (slot < ELL_CAP)
            ell[(size_t)(node0 + dl) * ELL_CAP + slot] = (ushort_t)(e & 0xFFFFu);
    }
    __syncthreads();
    if (tid < BUCK_SZ) {
        int node = node0 + tid;
        if (node < N_NODES) {
            int deg = lcnt[tid];
            cnt[node] = (deg > ELL_CAP) ? ELL_CAP : deg;
        }
    }
}

// ---------------- aggregation: h[n] = feat[n] + sum_{j in in-edges} feat[src_j] ----
// Standalone, high-occupancy (round-2 lesson). Quarter-wave (16 lanes) per
// node, uint4 per lane, 8 gathers in flight x 4 nodes/wave. ELL is ushort:
// 8 indices per 16B load. flags==nullptr -> featA; else bf16/f32 select.
__global__ __launch_bounds__(256) void agg_kernel(const ushort_t* __restrict__ featA,
                                                  const void* __restrict__ featB,
                                                  const int* __restrict__ flags,
                                                  const int* __restrict__ deg,
                                                  const ushort_t* __restrict__ ell,
                                                  ushort_t* __restrict__ hout) {
    int n = blockIdx.x * 16 + (threadIdx.x >> 4);
    int lane = threadIdx.x & 15;
    if (n >= N_NODES) return;
    const ushort_t* feat = featA;
    if (flags && !flags[0]) feat = (const ushort_t*)featB;
    const uint4* fp = reinterpret_cast<const uint4*>(feat);  // row = 16 x uint4
    uint4 v = fp[(size_t)n * 16 + lane];
    float a0 = bf2f((ushort_t)(v.x & 0xffff));
    float a1 = bf2f((ushort_t)(v.x >> 16));
    float a2 = bf2f((ushort_t)(v.y & 0xffff));
    float a3 = bf2f((ushort_t)(v.y >> 16));
    float a4 = bf2f((ushort_t)(v.z & 0xffff));
    float a5 = bf2f((ushort_t)(v.z >> 16));
    float a6 = bf2f((ushort_t)(v.w & 0xffff));
    float a7 = bf2f((ushort_t)(v.w >> 16));
    int e1 = deg[n];  // already capped at ELL_CAP by scatter
    const uint4* __restrict__ rp4 = reinterpret_cast<const uint4*>(ell + (size_t)n * ELL_CAP);
    const ushort_t* __restrict__ row = ell + (size_t)n * ELL_CAP;
    int j = 0;
#define ACC8(V) \
    a0 += bf2f((ushort_t)((V).x & 0xffff)); a1 += bf2f((ushort_t)((V).x >> 16)); \
    a2 += bf2f((ushort_t)((V).y & 0xffff)); a3 += bf2f((ushort_t)((V).y >> 16)); \
    a4 += bf2f((ushort_t)((V).z & 0xffff)); a5 += bf2f((ushort_t)((V).z >> 16)); \
    a6 += bf2f((ushort_t)((V).w & 0xffff)); a7 += bf2f((ushort_t)((V).w >> 16));
    for (; j + 8 <= e1; j += 8) {
        uint4 ra = rp4[j >> 3];  // 8 packed ushort indices
        int s0 = (int)(ra.x & 0xffff), s1 = (int)(ra.x >> 16);
        int s2 = (int)(ra.y & 0xffff), s3 = (int)(ra.y >> 16);
        int s4 = (int)(ra.z & 0xffff), s5 = (int)(ra.z >> 16);
        int s6 = (int)(ra.w & 0xffff), s7 = (int)(ra.w >> 16);
        uint4 g0 = fp[(size_t)s0 * 16 + lane];
        uint4 g1 = fp[(size_t)s1 * 16 + lane];
        uint4 g2 = fp[(size_t)s2 * 16 + lane];
        uint4 g3 = fp[(size_t)s3 * 16 + lane];
        uint4 g4 = fp[(size_t)s4 * 16 + lane];
        uint4 g5 = fp[(size_t)s5 * 16 + lane];
        uint4 g6 = fp[(size_t)s6 * 16 + lane];
        uint4 g7 = fp[(size_t)s7 * 16 + lane];
        ACC8(g0) ACC8(g1) ACC8(g2) ACC8(g3)
        ACC8(g4) ACC8(g5) ACC8(g6) ACC8(g7)
    }
    if (j + 4 <= e1) {
        uint2 ra = *reinterpret_cast<const uint2*>(row + j);  // 4 packed indices
        int s0 = (int)(ra.x & 0xffff), s1 = (int)(ra.x >> 16);
        int s2 = (int)(ra.y & 0xffff), s3 = (int)(ra.y >> 16);
        uint4 g0 = fp[(size_t)s0 * 16 + lane];
        uint4 g1 = fp[(size_t)s1 * 16 + lane];
        uint4 g2 = fp[(size_t)s2 * 16 + lane];
        uint4 g3 = fp[(size_t)s3 * 16 + lane];
        ACC8(g0) ACC8(g1) ACC8(g2) ACC8(g3)
        j += 4;
    }
    for (; j < e1; ++j) {
        int s = (int)row[j];
        uint4 g0 = fp[(size_t)s * 16 + lane];
        ACC8(g0)
    }
#undef ACC8
    uint4 o;
    o.x = (uint_t)f2bf(a0) | ((uint_t)f2bf(a1) << 16);
    o.y = (uint_t)f2bf(a2) | ((uint_t)f2bf(a3) << 16);
    o.z = (uint_t)f2bf(a4) | ((uint_t)f2bf(a5) << 16);
    o.w = (uint_t)f2bf(a6) | ((uint_t)f2bf(a7) << 16);
    reinterpret_cast<uint4*>(hout)[(size_t)n * 16 + lane] = o;
}

// ---------------- fused MLP layer 1: hout = relu(relu(hin@Wa+ba)@Wb+bb) --------
__global__ __launch_bounds__(256) void mlp_kernel(const ushort_t* __restrict__ hin,
                                                  const ushort_t* __restrict__ wpA,
                                                  const float* __restrict__ ba,
                                                  const ushort_t* __restrict__ wpB,
                                                  const float* __restrict__ bb,
                                                  ushort_t* __restrict__ hout) {
    __shared__ ushort_t As[64 * LDA];
    int tid = threadIdx.x;
    int wave = tid >> 6;
    int lane = tid & 63;
    int quad = lane >> 4;
    int cl = lane & 15;
    int row0 = blockIdx.x * 64;

    bf16x8 B1[2][4], B2[2][4];
#pragma unroll
    for (int ti = 0; ti < 2; ++ti) {
        int t = 2 * wave + ti;
#pragma unroll
        for (int s = 0; s < 4; ++s) {
            B1[ti][s] = as_bf16x8(reinterpret_cast<const uint4*>(wpA)[(s * 8 + t) * 64 + lane]);
            B2[ti][s] = as_bf16x8(reinterpret_cast<const uint4*>(wpB)[(s * 8 + t) * 64 + lane]);
        }
    }

    for (int i = tid; i < 64 * 16; i += 256) {
        int r = i >> 4, c8 = i & 15;
        uint4 v = make_uint4(0u, 0u, 0u, 0u);
        int gr = row0 + r;
        if (gr < N_NODES)
            v = reinterpret_cast<const uint4*>(hin + (size_t)gr * DIM)[c8];
        *reinterpret_cast<uint4*>(&As[r * LDA + c8 * 8]) = v;
    }
    __syncthreads();

    f32x4 acc[4][2];
#pragma unroll
    for (int m = 0; m < 4; ++m)
#pragma unroll
        for (int ti = 0; ti < 2; ++ti)
#pragma unroll
            for (int r = 0; r < 4; ++r) acc[m][ti][r] = 0.f;

#pragma unroll
    for (int s = 0; s < 4; ++s) {
#pragma unroll
        for (int m = 0; m < 4; ++m) {
            bf16x8 a = *reinterpret_cast<const bf16x8*>(&As[(m * 16 + cl) * LDA + s * 32 + quad * 8]);
#pragma unroll
            for (int ti = 0; ti < 2; ++ti)
                acc[m][ti] = __builtin_amdgcn_mfma_f32_16x16x32_bf16(a, B1[ti][s], acc[m][ti], 0, 0, 0);
        }
    }
    __syncthreads();

#pragma unroll
    for (int ti = 0; ti < 2; ++ti) {
        int col = 32 * wave + ti * 16 + cl;
        float bv = ba[col];
#pragma unroll
        for (int m = 0; m < 4; ++m)
#pragma unroll
            for (int r = 0; r < 4; ++r) {
                float v = acc[m][ti][r] + bv;
                As[(m * 16 + quad * 4 + r) * LDA + col] = f2bf(fmaxf(v, 0.f));
            }
    }
    __syncthreads();

#pragma unroll
    for (int m = 0; m < 4; ++m)
#pragma unroll
        for (int ti = 0; ti < 2; ++ti)
#pragma unroll
            for (int r = 0; r < 4; ++r) acc[m][ti][r] = 0.f;

#pragma unroll
    for (int s = 0; s < 4; ++s) {
#pragma unroll
        for (int m = 0; m < 4; ++m) {
            bf16x8 a = *reinterpret_cast<const bf16x8*>(&As[(m * 16 + cl) * LDA + s * 32 + quad * 8]);
#pragma unroll
            for (int ti = 0; ti < 2; ++ti)
                acc[m][ti] = __builtin_amdgcn_mfma_f32_16x16x32_bf16(a, B2[ti][s], acc[m][ti], 0, 0, 0);
        }
    }

#pragma unroll
    for (int ti = 0; ti < 2; ++ti) {
        int col = 32 * wave + ti * 16 + cl;
        float bv = bb[col];
#pragma unroll
        for (int m = 0; m < 4; ++m)
#pragma unroll
            for (int r = 0; r < 4; ++r) {
                int gr = row0 + m * 16 + quad * 4 + r;
                if (gr < N_NODES) {
                    float v = acc[m][ti][r] + bv;
                    hout[(size_t)gr * DIM + col] = f2bf(fmaxf(v, 0.f));
                }
            }
    }
}

// ---------------- fused MLP layer 2 + per-graph pooling ----------------
__global__ __launch_bounds__(256) void mlp_pool_kernel(const ushort_t* __restrict__ hin,
                                                       const ushort_t* __restrict__ wpA,
                                                       const float* __restrict__ ba,
                                                       const ushort_t* __restrict__ wpB,
                                                       const float* __restrict__ bb,
                                                       const int* __restrict__ batch32,
                                                       float* __restrict__ gsum) {
    __shared__ ushort_t As[64 * LDA];
    int tid = threadIdx.x;
    int wave = tid >> 6;
    int lane = tid & 63;
    int quad = lane >> 4;
    int cl = lane & 15;
    int row0 = blockIdx.x * 64;

    bf16x8 B1[2][4], B2[2][4];
#pragma unroll
    for (int ti = 0; ti < 2; ++ti) {
        int t = 2 * wave + ti;
#pragma unroll
        for (int s = 0; s < 4; ++s) {
            B1[ti][s] = as_bf16x8(reinterpret_cast<const uint4*>(wpA)[(s * 8 + t) * 64 + lane]);
            B2[ti][s] = as_bf16x8(reinterpret_cast<const uint4*>(wpB)[(s * 8 + t) * 64 + lane]);
        }
    }

    for (int i = tid; i < 64 * 16; i += 256) {
        int r = i >> 4, c8 = i & 15;
        uint4 v = make_uint4(0u, 0u, 0u, 0u);
        int gr = row0 + r;
        if (gr < N_NODES)
            v = reinterpret_cast<const uint4*>(hin + (size_t)gr * DIM)[c8];
        *reinterpret_cast<uint4*>(&As[r * LDA + c8 * 8]) = v;
    }
    __syncthreads();

    f32x4 acc[4][2];
#pragma unroll
    for (int m = 0; m < 4; ++m)
#pragma unroll
        for (int ti = 0; ti < 2; ++ti)
#pragma unroll
            for (int r = 0; r < 4; ++r) acc[m][ti][r] = 0.f;

#pragma unroll
    for (int s = 0; s < 4; ++s) {
#pragma unroll
        for (int m = 0; m < 4; ++m) {
            bf16x8 a = *reinterpret_cast<const bf16x8*>(&As[(m * 16 + cl) * LDA + s * 32 + quad * 8]);
#pragma unroll
            for (int ti = 0; ti < 2; ++ti)
                acc[m][ti] = __builtin_amdgcn_mfma_f32_16x16x32_bf16(a, B1[ti][s], acc[m][ti], 0, 0, 0);
        }
    }
    __syncthreads();

#pragma unroll
    for (int ti = 0; ti < 2; ++ti) {
        int col = 32 * wave + ti * 16 + cl;
        float bv = ba[col];
#pragma unroll
        for (int m = 0; m < 4; ++m)
#pragma unroll
            for (int r = 0; r < 4; ++r) {
                float v = acc[m][ti][r] + bv;
                As[(m * 16 + quad * 4 + r) * LDA + col] = f2bf(fmaxf(v, 0.f));
            }
    }
    __syncthreads();

#pragma unroll
    for (int m = 0; m < 4; ++m)
#pragma unroll
        for (int ti = 0; ti < 2; ++ti)
#pragma unroll
            for (int r = 0; r < 4; ++r) acc[m][ti][r] = 0.f;

#pragma unroll
    for (int s = 0; s < 4; ++s) {
#pragma unroll
        for (int m = 0; m < 4; ++m) {
            bf16x8 a = *reinterpret_cast<const bf16x8*>(&As[(m * 16 + cl) * LDA + s * 32 + quad * 8]);
#pragma unroll
            for (int ti = 0; ti < 2; ++ti)
                acc[m][ti] = __builtin_amdgcn_mfma_f32_16x16x32_bf16(a, B2[ti][s], acc[m][ti], 0, 0, 0);
        }
    }
    __syncthreads();  // all As reads of GEMM2 done before epilogue overwrite

#pragma unroll
    for (int ti = 0; ti < 2; ++ti) {
        int col = 32 * wave + ti * 16 + cl;
        float bv = bb[col];
#pragma unroll
        for (int m = 0; m < 4; ++m)
#pragma unroll
            for (int r = 0; r < 4; ++r) {
                float v = acc[m][ti][r] + bv;
                As[(m * 16 + quad * 4 + r) * LDA + col] = f2bf(fmaxf(v, 0.f));
            }
    }
    __syncthreads();

    // pooling: thread t handles col c over 32 rows; flush per graph segment
    int c = tid & 127;
    int rbase = (tid >> 7) * 32;
    float accp = 0.f;
    int curg = -1;
    for (int r = rbase; r < rbase + 32; ++r) {
        int gr = row0 + r;
        if (gr >= N_NODES) break;
        int g = batch32[gr];
        if (g != curg) {
            if (curg >= 0) atomicAdd(&gsum[curg * DIM + c], accp);
            curg = g;
            accp = 0.f;
        }
        accp += bf2f(As[r * LDA + c]);
    }
    if (curg >= 0) atomicAdd(&gsum[curg * DIM + c], accp);
}

// ---------------- final FC: out[g] = (gsum[g]/count[g]) @ Wfc + bfc ----------------
__global__ __launch_bounds__(64) void fc_kernel(const float* __restrict__ gsum,
                                                const int* __restrict__ batch,
                                                const float* __restrict__ params,
                                                const int* __restrict__ flags,
                                                void* __restrict__ out) {
    int g = blockIdx.x;
    int l = threadIdx.x;
    int lo = 0, hi = N_NODES;
    while (lo < hi) { int mid = (lo + hi) >> 1; if (batch[mid] < g) lo = mid + 1; else hi = mid; }
    int start = lo;
    hi = N_NODES;
    while (lo < hi) { int mid = (lo + hi) >> 1; if (batch[mid] < g + 1) lo = mid + 1; else hi = mid; }
    int cnt = lo - start;
    float inv = 1.0f / (float)(cnt > 0 ? cnt : 1);
    float m0 = gsum[g * DIM + l] * inv;
    float m1 = gsum[g * DIM + 64 + l] * inv;
    float p0 = m0 * params[512 + l * 2 + 0] + m1 * params[512 + (64 + l) * 2 + 0];
    float p1 = m0 * params[512 + l * 2 + 1] + m1 * params[512 + (64 + l) * 2 + 1];
#pragma unroll
    for (int off = 32; off > 0; off >>= 1) {
        p0 += __shfl_down(p0, off, 64);
        p1 += __shfl_down(p1, off, 64);
    }
    if (l == 0) {
        float o0 = p0 + params[768];
        float o1 = p1 + params[769];
        if (flags[0]) {
            ((float*)out)[g * 2 + 0] = o0;
            ((float*)out)[g * 2 + 1] = o1;
        } else {
            ((ushort_t*)out)[g * 2 + 0] = f2bf(o0);
            ((ushort_t*)out)[g * 2 + 1] = f2bf(o1);
        }
    }
}

extern "C" void kernel_launch(void* const* d_in, const int* in_sizes, int n_in,
                              void* d_out, int out_size, void* d_ws, size_t ws_size,
                              hipStream_t stream) {
    const void* x = d_in[0];
    const void* ei = d_in[1];
    const void* batch = d_in[2];
    const void* W1a = d_in[3];
    const void* b1a = d_in[4];
    const void* W1b = d_in[5];
    const void* b1b = d_in[6];
    const void* W2a = d_in[7];
    const void* b2a = d_in[8];
    const void* W2b = d_in[9];
    const void* b2b = d_in[10];
    const void* Wfc = d_in[11];
    const void* bfc = d_in[12];

    // Workspace layout (~38 MB, all chunks 16B-aligned)
    char* base = (char*)d_ws;
    ushort_t* hX = (ushort_t*)base;   base += (size_t)N_NODES * DIM * 2;       // 12.8 MB (f32 input only)
    ushort_t* hA = (ushort_t*)base;   base += (size_t)N_NODES * DIM * 2;       // 12.8 MB
    ushort_t* ell = (ushort_t*)base;  base += (size_t)N_NODES * ELL_CAP * 2;   // 6.4 MB (ushort)
    uint_t* fifo = (uint_t*)base;     base += (size_t)NBUCK * FIFO_CAP * 4;    // 4 MB
    int* cnt = (int*)base;            base += (size_t)N_NODES * 4;
    int* batch32 = (int*)base;        base += (size_t)N_NODES * 4;
    int* gcnt = (int*)base;           base += NBUCK * 4;
    ushort_t* wp = (ushort_t*)base;   base += 4 * 16384 * 2;
    float* params = (float*)base;     base += 772 * 4;
    float* gsum = (float*)base;       base += (size_t)NUM_GRAPHS * DIM * 4;    // 256 KB
    int* flags = (int*)base;          base += 16;

    ushort_t* wpA1 = wp;
    ushort_t* wpB1 = wp + 16384;
    ushort_t* wpA2 = wp + 2 * 16384;
    ushort_t* wpB2 = wp + 3 * 16384;

    // Zero bucket counters + device-side dtype detection (1 block)
    zero_detect_kernel<<<1, 256, 0, stream>>>(gcnt, x, ei, flags);
    // Pass A: edge partition into 256 packed bucket-FIFOs + canonicalization
    prep_all_kernel<<<PREP_TOTAL, 256, 0, stream>>>(x, batch, ei, W1a, W1b, W2a, W2b,
                                                    b1a, b1b, b2a, b2b, Wfc, bfc, flags,
                                                    hX, wp, batch32, params, gcnt, fifo);
    // Pass B: per-bucket ELL scatter (LDS slot counters, unsorted, ushort)
    scatter_kernel<<<NBUCK, 256, 0, stream>>>(fifo, gcnt, cnt, ell, gsum);

    // Layer 1: agg(x)->hA (reads raw input in place when bf16), mlp in-place on hA
    agg_kernel<<<(N_NODES + 15) / 16, 256, 0, stream>>>(hX, x, flags, cnt, ell, hA);
    mlp_kernel<<<(N_NODES + 63) / 64, 256, 0, stream>>>(hA, wpA1, params + 0, wpB1, params + 128, hA);
    // Layer 2: agg(hA)->hX, then MLP+pool fused (no h2 global write)
    agg_kernel<<<(N_NODES + 15) / 16, 256, 0, stream>>>(hA, hA, nullptr, cnt, ell, hX);
    mlp_pool_kernel<<<(N_NODES + 63) / 64, 256, 0, stream>>>(hX, wpA2, params + 256, wpB2, params + 384,
                                                             batch32, gsum);
    // Final FC from pooled sums
    fc_kernel<<<NUM_GRAPHS, 64, 0, stream>>>(gsum, batch32, params, flags, d_out);
}